// Round 1
// 275.530 us; speedup vs baseline: 1.1365x; 1.1365x over previous
//
#include <hip/hip_runtime.h>
#include <math.h>

#define HEADS 4
#define BATCH 8
#define SEQ   1024
#define CH    256
#define DH    64
#define RB    16          // q rows per block
#define NTHR  512         // 8 waves
#define SSTR  1032        // Sraw row stride in u16 (2064 B, 16B-mult)

typedef float  floatx4  __attribute__((ext_vector_type(4)));
typedef short  shortx8  __attribute__((ext_vector_type(8)));

__device__ __forceinline__ unsigned short f2bf(float f) {
    unsigned u = __float_as_uint(f);
    unsigned r = u + 0x7FFFu + ((u >> 16) & 1u);   // RNE; -inf stays -inf
    return (unsigned short)(r >> 16);
}
__device__ __forceinline__ float bf2f(unsigned short h) {
    return __uint_as_float(((unsigned)h) << 16);
}
__device__ __forceinline__ shortx8 pack8(float4 a, float4 b) {
    shortx8 r;
    r[0] = (short)f2bf(a.x); r[1] = (short)f2bf(a.y);
    r[2] = (short)f2bf(a.z); r[3] = (short)f2bf(a.w);
    r[4] = (short)f2bf(b.x); r[5] = (short)f2bf(b.y);
    r[6] = (short)f2bf(b.z); r[7] = (short)f2bf(b.w);
    return r;
}

// ---- prologue: one-time f32->bf16 staging into workspace.
// qb, kb: bf16, same [B,N,C] layout.  vt: bf16 V transposed per head: [b][h][d][n].
// Removes the per-block re-conversion (x64 blocks) and turns every MFMA
// operand in the main kernel into a single aligned 16B load.
__global__ __launch_bounds__(256)
void prep(const float* __restrict__ q, const float* __restrict__ k,
          const float* __restrict__ v, unsigned short* __restrict__ qb,
          unsigned short* __restrict__ kb, unsigned short* __restrict__ vt)
{
    const int t = threadIdx.x;
    const int bid = blockIdx.x;
    if (bid < 2048) {                       // q (0..1023) / k (1024..2047) convert
        const float* src = (bid < 1024) ? q : k;
        unsigned short* dst = (bid < 1024) ? qb : kb;
        size_t idx = (size_t)(bid & 1023) * 2048 + (size_t)t * 8;
        float4 a = *(const float4*)(src + idx);
        float4 b = *(const float4*)(src + idx + 4);
        *(shortx8*)(dst + idx) = pack8(a, b);
        return;
    }
    // V transpose-convert: block = (b, h, 64-row n-tile)
    __shared__ unsigned short tl[64][68];   // pad 68: 8B-aligned rows, bank-spread col reads
    const int vb = bid - 2048;
    const int nt = vb & 15, h = (vb >> 4) & 3, b = vb >> 6;
    const int n0 = nt * 64;
    const float* vsrc = v + ((size_t)(b * SEQ + n0)) * CH + h * DH;
    #pragma unroll
    for (int it = 0; it < 4; ++it) {
        int fid = it * 256 + t;
        int n = fid >> 4, cc = (fid & 15) * 4;
        float4 x = *(const float4*)(vsrc + (size_t)n * CH + cc);   // coalesced
        tl[n][cc]     = f2bf(x.x);
        tl[n][cc + 1] = f2bf(x.y);
        tl[n][cc + 2] = f2bf(x.z);
        tl[n][cc + 3] = f2bf(x.w);
    }
    __syncthreads();
    unsigned short* vout = vt + ((size_t)((b * HEADS + h) * DH)) * SEQ + n0;
    #pragma unroll
    for (int it = 0; it < 2; ++it) {
        int cid = it * 256 + t;
        int d = cid >> 3, nc = cid & 7;
        shortx8 r;
        #pragma unroll
        for (int j = 0; j < 8; ++j) r[j] = (short)tl[nc * 8 + j][d];
        *(shortx8*)(vout + (size_t)d * SEQ + nc * 8) = r;          // coalesced 16B
    }
}

__global__ __launch_bounds__(NTHR, 8)
void attn_mfma(const unsigned short* __restrict__ qb,
               const unsigned short* __restrict__ kbf,
               const unsigned short* __restrict__ vt,
               const void* __restrict__ maskp,
               const float* __restrict__ dis, float* __restrict__ out,
               float* __restrict__ pout)
{
    __shared__ unsigned short Sraw[RB][SSTR];    // 33 KB: raw scores -> exp
    __shared__ float Opart[RB][65];              // 4.2 KB partial O (pad 65)
    __shared__ float invs[RB];

    const int t   = threadIdx.x;
    const int bid = blockIdx.x;
    const int nb  = bid & 63;          // 64 row-tiles per (h,b)
    const int hb  = bid >> 6;
    const int b   = hb & (BATCH - 1);
    const int h   = hb >> 3;
    const int n0  = nb * RB;

    const int lane = t & 63;
    const int w    = t >> 6;       // wave 0..7
    const int ln   = lane & 15;    // fragment m / n index
    const int qd   = lane >> 4;    // quad -> k-group / D row group

    // ---- inline mask-dtype detect: int32 bool => misaligned bytes all 0.
    int fl;
    {
        const unsigned* mw = (const unsigned*)maskp;
        int found = 0;
        #pragma unroll
        for (int j = 0; j < 16; ++j)
            if (mw[lane * 16 + j] & 0xFFFFFF00u) found = 1;
        fl = (__ballot(found != 0) != 0ULL) ? 1 : 0;   // 1 => byte mask
    }
    const unsigned char* mask8  = (const unsigned char*)maskp;
    const int*           mask32 = (const int*)maskp;

    // ---- Q A-frags: two aligned 16B loads (pre-converted bf16) ----
    const unsigned short* qrow = qb + ((size_t)(b * SEQ + n0 + ln)) * CH + h * DH;
    shortx8 aq0 = *(const shortx8*)(qrow + qd * 8);
    shortx8 aq1 = *(const shortx8*)(qrow + 32 + qd * 8);

    const unsigned short* kbase = kbf + ((size_t)(b * SEQ)) * CH + h * DH;
    const unsigned short* vbase = vt + ((size_t)((b * HEADS + h) * DH)) * SEQ;

    // ---- Pass 1: S = mask ? -inf : (Q K^T + dis)/8 -> bf16 LDS. No barriers.
    #pragma unroll 2
    for (int mc = 0; mc < 8; ++mc) {
        const int mg = mc * 128 + w * 16 + ln;        // score col == K row
        const size_t dibase = ((size_t)(b * SEQ + n0 + qd * 4)) * SEQ + mg;
        float dv[4]; int mk[4];
        #pragma unroll
        for (int r = 0; r < 4; ++r) dv[r] = dis[dibase + (size_t)r * SEQ];
        if (fl) {
            #pragma unroll
            for (int r = 0; r < 4; ++r) mk[r] = mask8[dibase + (size_t)r * SEQ];
        } else {
            #pragma unroll
            for (int r = 0; r < 4; ++r) mk[r] = mask32[dibase + (size_t)r * SEQ];
        }
        const unsigned short* krow = kbase + (size_t)mg * CH;  // L2-resident, bf16
        shortx8 b0 = *(const shortx8*)(krow + qd * 8);
        shortx8 b1 = *(const shortx8*)(krow + 32 + qd * 8);
        floatx4 acc = {0.f, 0.f, 0.f, 0.f};
        acc = __builtin_amdgcn_mfma_f32_16x16x32_bf16(aq0, b0, acc, 0, 0, 0);
        acc = __builtin_amdgcn_mfma_f32_16x16x32_bf16(aq1, b1, acc, 0, 0, 0);
        #pragma unroll
        for (int r = 0; r < 4; ++r) {                 // D: col=ln, row=qd*4+r
            float sc = mk[r] ? -INFINITY : (acc[r] + dv[r]) * 0.125f;
            Sraw[qd * 4 + r][mg] = f2bf(sc);
        }
    }
    __syncthreads();

    // ---- Pass 2: softmax per row (32 threads/row), exp stored in-place ----
    {
        const int r = t >> 5, l = t & 31;
        float mx = -INFINITY;
        #pragma unroll
        for (int j = 0; j < 4; ++j) {
            shortx8 sv = *(const shortx8*)&Sraw[r][j * 256 + l * 8];
            #pragma unroll
            for (int e = 0; e < 8; ++e) mx = fmaxf(mx, bf2f((unsigned short)sv[e]));
        }
        #pragma unroll
        for (int off = 16; off; off >>= 1) mx = fmaxf(mx, __shfl_xor(mx, off, 32));
        float sum = 0.f;
        #pragma unroll
        for (int j = 0; j < 4; ++j) {
            shortx8 sv = *(const shortx8*)&Sraw[r][j * 256 + l * 8];
            shortx8 ev;
            #pragma unroll
            for (int e = 0; e < 8; ++e) {
                float x = __expf(bf2f((unsigned short)sv[e]) - mx);  // exp(-inf)=0
                sum += x;
                ev[e] = (short)f2bf(x);
            }
            *(shortx8*)&Sraw[r][j * 256 + l * 8] = ev;
        }
        #pragma unroll
        for (int off = 16; off; off >>= 1) sum += __shfl_xor(sum, off, 32);
        if (l == 0) invs[r] = 1.0f / sum;
    }
    __syncthreads();

    // ---- Pass 2b: write normalized p_attn (float2 per thread, coalesced) ----
    {
        float* prow = pout + ((size_t)((h * BATCH + b) * SEQ + n0)) * SEQ;
        #pragma unroll
        for (int i = 0; i < RB; ++i) {
            const float inv = invs[i];
            unsigned pk = *(const unsigned*)&Sraw[i][t * 2];
            float2 pv = { bf2f((unsigned short)(pk & 0xFFFFu)) * inv,
                          bf2f((unsigned short)(pk >> 16)) * inv };
            *(float2*)(prow + (size_t)i * SEQ + t * 2) = pv;
        }
    }

    // ---- Pass 3: O = (E V) * inv. m-range split across wave halves. ----
    // V fragment is now ONE 16B load from the transposed bf16 staging buffer.
    const int hm = w >> 2;            // m-half 0/1
    const int c  = (w & 3) * 16;      // output col slice
    floatx4 acco = {0.f, 0.f, 0.f, 0.f};
    const unsigned short* vcol = vbase + (size_t)(c + ln) * SEQ;
    #pragma unroll 2
    for (int mc = 0; mc < 8; ++mc) {
        #pragma unroll
        for (int s = 0; s < 2; ++s) {
            const int kk = hm * 512 + mc * 64 + s * 32 + qd * 8;
            shortx8 af  = *(const shortx8*)&Sraw[ln][kk];     // A[m=ln][k]
            shortx8 bfv = *(const shortx8*)(vcol + kk);       // B[k][n=c+ln]
            acco = __builtin_amdgcn_mfma_f32_16x16x32_bf16(af, bfv, acco, 0, 0, 0);
        }
    }
    if (hm == 1) {
        #pragma unroll
        for (int r = 0; r < 4; ++r) Opart[qd * 4 + r][c + ln] = acco[r];
    }
    __syncthreads();
    if (hm == 0) {
        #pragma unroll
        for (int r = 0; r < 4; ++r) {
            int row = qd * 4 + r;
            out[((size_t)(b * SEQ + n0 + row)) * CH + h * DH + c + ln]
                = (acco[r] + Opart[row][c + ln]) * invs[row];
        }
    }
}

extern "C" void kernel_launch(void* const* d_in, const int* in_sizes, int n_in,
                              void* d_out, int out_size, void* d_ws, size_t ws_size,
                              hipStream_t stream) {
    const float* q    = (const float*)d_in[0];
    const float* k    = (const float*)d_in[1];
    const float* v    = (const float*)d_in[2];
    const void*  mask = d_in[3];
    const float* dis  = (const float*)d_in[4];
    float* out  = (float*)d_out;
    float* pout = out + (size_t)BATCH * SEQ * CH;   // p_attn after out

    // workspace staging: qb | kb | vt, each 2M bf16 (4 MB) => 12 MB total
    unsigned short* qb  = (unsigned short*)d_ws;
    unsigned short* kbw = qb  + (size_t)BATCH * SEQ * CH;
    unsigned short* vtw = kbw + (size_t)BATCH * SEQ * CH;
    (void)ws_size;

    prep<<<2560, 256, 0, stream>>>(q, k, v, qb, kbw, vtw);
    attn_mfma<<<HEADS * BATCH * (SEQ / RB), NTHR, 0, stream>>>(
        qb, kbw, vtw, mask, dis, out, pout);
}

// Round 2
// 269.150 us; speedup vs baseline: 1.1634x; 1.0237x over previous
//
#include <hip/hip_runtime.h>
#include <math.h>

#define HEADS 4
#define BATCH 8
#define SEQ   1024
#define CH    256
#define DH    64
#define RB    16          // q rows per block
#define NTHR  512         // 8 waves
#define SSTR  1032        // Sraw row stride in u16 (2064 B, 16B-mult)

typedef float  floatx4  __attribute__((ext_vector_type(4)));
typedef float  floatx2  __attribute__((ext_vector_type(2)));
typedef short  shortx8  __attribute__((ext_vector_type(8)));

__device__ __forceinline__ unsigned short f2bf(float f) {
    unsigned u = __float_as_uint(f);
    unsigned r = u + 0x7FFFu + ((u >> 16) & 1u);   // RNE; -inf stays -inf
    return (unsigned short)(r >> 16);
}
__device__ __forceinline__ float bf2f(unsigned short h) {
    return __uint_as_float(((unsigned)h) << 16);
}
__device__ __forceinline__ shortx8 pack8(float4 a, float4 b) {
    shortx8 r;
    r[0] = (short)f2bf(a.x); r[1] = (short)f2bf(a.y);
    r[2] = (short)f2bf(a.z); r[3] = (short)f2bf(a.w);
    r[4] = (short)f2bf(b.x); r[5] = (short)f2bf(b.y);
    r[6] = (short)f2bf(b.z); r[7] = (short)f2bf(b.w);
    return r;
}

// ---- prologue: one-time f32->bf16 staging into workspace.
// qb, kb: bf16, same [B,N,C] layout.  vt: bf16 V transposed per head: [b][h][d][n].
__global__ __launch_bounds__(256)
void prep(const float* __restrict__ q, const float* __restrict__ k,
          const float* __restrict__ v, unsigned short* __restrict__ qb,
          unsigned short* __restrict__ kb, unsigned short* __restrict__ vt)
{
    const int t = threadIdx.x;
    const int bid = blockIdx.x;
    if (bid < 2048) {                       // q (0..1023) / k (1024..2047) convert
        const float* src = (bid < 1024) ? q : k;
        unsigned short* dst = (bid < 1024) ? qb : kb;
        size_t idx = (size_t)(bid & 1023) * 2048 + (size_t)t * 8;
        float4 a = *(const float4*)(src + idx);
        float4 b = *(const float4*)(src + idx + 4);
        *(shortx8*)(dst + idx) = pack8(a, b);
        return;
    }
    // V transpose-convert: block = (b, h, 64-row n-tile)
    __shared__ unsigned short tl[64][68];
    const int vb = bid - 2048;
    const int nt = vb & 15, h = (vb >> 4) & 3, b = vb >> 6;
    const int n0 = nt * 64;
    const float* vsrc = v + ((size_t)(b * SEQ + n0)) * CH + h * DH;
    #pragma unroll
    for (int it = 0; it < 4; ++it) {
        int fid = it * 256 + t;
        int n = fid >> 4, cc = (fid & 15) * 4;
        float4 x = *(const float4*)(vsrc + (size_t)n * CH + cc);   // coalesced
        tl[n][cc]     = f2bf(x.x);
        tl[n][cc + 1] = f2bf(x.y);
        tl[n][cc + 2] = f2bf(x.z);
        tl[n][cc + 3] = f2bf(x.w);
    }
    __syncthreads();
    unsigned short* vout = vt + ((size_t)((b * HEADS + h) * DH)) * SEQ + n0;
    #pragma unroll
    for (int it = 0; it < 2; ++it) {
        int cid = it * 256 + t;
        int d = cid >> 3, nc = cid & 7;
        shortx8 r;
        #pragma unroll
        for (int j = 0; j < 8; ++j) r[j] = (short)tl[nc * 8 + j][d];
        *(shortx8*)(vout + (size_t)d * SEQ + nc * 8) = r;          // coalesced 16B
    }
}

// Block = (b, 16-row q tile); loops over all 4 heads internally so the
// dis tile (32 f32/thread in VGPRs) and mask (1 bit/score in one u32)
// are fetched from HBM exactly ONCE instead of once per head.
__global__ __launch_bounds__(NTHR, 4)
void attn_mfma(const unsigned short* __restrict__ qb,
               const unsigned short* __restrict__ kbf,
               const unsigned short* __restrict__ vt,
               const void* __restrict__ maskp,
               const float* __restrict__ dis, float* __restrict__ out,
               float* __restrict__ pout)
{
    __shared__ unsigned short Sraw[RB][SSTR];    // 33 KB: raw scores -> exp
    __shared__ float Opart[RB][65];              // 4.2 KB partial O (pad 65)
    __shared__ float invs[RB];

    const int t   = threadIdx.x;
    const int bid = blockIdx.x;
    // b = bid & 7: the 64 same-b blocks share K/V (1 MB) and land on one XCD
    // under round-robin bid%8 dispatch -> K/V stays L2-resident per XCD.
    const int b   = bid & (BATCH - 1);
    const int nb  = bid >> 3;
    const int n0  = nb * RB;

    const int lane = t & 63;
    const int w    = t >> 6;       // wave 0..7
    const int ln   = lane & 15;    // fragment m / n index
    const int qd   = lane >> 4;    // quad -> k-group / D row group

    // ---- inline mask-dtype detect: int32 bool => misaligned bytes all 0.
    int fl;
    {
        const unsigned* mw = (const unsigned*)maskp;
        int found = 0;
        #pragma unroll
        for (int j = 0; j < 16; ++j)
            if (mw[lane * 16 + j] & 0xFFFFFF00u) found = 1;
        fl = (__ballot(found != 0) != 0ULL) ? 1 : 0;   // 1 => byte mask
    }
    const unsigned char* mask8  = (const unsigned char*)maskp;
    const int*           mask32 = (const int*)maskp;

    // ---- dis tile + mask into registers, ONCE for all 4 heads ----
    // dreg[mc*4+r] = dis[n0+qd*4+r][mc*128+w*16+ln]; mbits bit (mc*4+r) = mask
    float dreg[32];
    unsigned mbits = 0;
    {
        const size_t dib0 = ((size_t)(b * SEQ + n0 + qd * 4)) * SEQ + w * 16 + ln;
        #pragma unroll
        for (int mc = 0; mc < 8; ++mc) {
            #pragma unroll
            for (int r = 0; r < 4; ++r) {
                const size_t idx = dib0 + (size_t)r * SEQ + mc * 128;
                dreg[mc * 4 + r] = dis[idx];
                int mk = fl ? (int)mask8[idx] : mask32[idx];
                mbits |= (mk ? 1u : 0u) << (mc * 4 + r);
            }
        }
    }

    #pragma unroll 1
    for (int h = 0; h < HEADS; ++h) {
        // ---- Q A-frags: two aligned 16B loads (pre-converted bf16) ----
        const unsigned short* qrow =
            qb + ((size_t)(b * SEQ + n0 + ln)) * CH + h * DH;
        shortx8 aq0 = *(const shortx8*)(qrow + qd * 8);
        shortx8 aq1 = *(const shortx8*)(qrow + 32 + qd * 8);

        const unsigned short* kbase = kbf + ((size_t)(b * SEQ)) * CH + h * DH;
        const unsigned short* vbase = vt + ((size_t)((b * HEADS + h) * DH)) * SEQ;

        // ---- Pass 1: S = mask ? -inf : (Q K^T + dis)/8 -> bf16 LDS ----
        #pragma unroll
        for (int mc = 0; mc < 8; ++mc) {
            const int mg = mc * 128 + w * 16 + ln;        // score col == K row
            const unsigned short* krow = kbase + (size_t)mg * CH;  // L2, bf16
            shortx8 b0 = *(const shortx8*)(krow + qd * 8);
            shortx8 b1 = *(const shortx8*)(krow + 32 + qd * 8);
            floatx4 acc = {0.f, 0.f, 0.f, 0.f};
            acc = __builtin_amdgcn_mfma_f32_16x16x32_bf16(aq0, b0, acc, 0, 0, 0);
            acc = __builtin_amdgcn_mfma_f32_16x16x32_bf16(aq1, b1, acc, 0, 0, 0);
            #pragma unroll
            for (int r = 0; r < 4; ++r) {                 // D: col=ln, row=qd*4+r
                float sc = ((mbits >> (mc * 4 + r)) & 1u)
                               ? -INFINITY
                               : (acc[r] + dreg[mc * 4 + r]) * 0.125f;
                Sraw[qd * 4 + r][mg] = f2bf(sc);
            }
        }
        __syncthreads();

        // ---- Pass 2: softmax per row (32 threads/row), exp in-place ----
        {
            const int r = t >> 5, l = t & 31;
            float mx = -INFINITY;
            #pragma unroll
            for (int j = 0; j < 4; ++j) {
                shortx8 sv = *(const shortx8*)&Sraw[r][j * 256 + l * 8];
                #pragma unroll
                for (int e = 0; e < 8; ++e)
                    mx = fmaxf(mx, bf2f((unsigned short)sv[e]));
            }
            #pragma unroll
            for (int off = 16; off; off >>= 1)
                mx = fmaxf(mx, __shfl_xor(mx, off, 32));
            float sum = 0.f;
            #pragma unroll
            for (int j = 0; j < 4; ++j) {
                shortx8 sv = *(const shortx8*)&Sraw[r][j * 256 + l * 8];
                shortx8 ev;
                #pragma unroll
                for (int e = 0; e < 8; ++e) {
                    float x = __expf(bf2f((unsigned short)sv[e]) - mx);
                    sum += x;
                    ev[e] = (short)f2bf(x);
                }
                *(shortx8*)&Sraw[r][j * 256 + l * 8] = ev;
            }
            #pragma unroll
            for (int off = 16; off; off >>= 1) sum += __shfl_xor(sum, off, 32);
            if (l == 0) invs[r] = 1.0f / sum;
        }
        __syncthreads();

        // ---- Pass 2b: write normalized p_attn (nontemporal: never re-read) ----
        {
            float* prow = pout + ((size_t)((h * BATCH + b) * SEQ + n0)) * SEQ;
            #pragma unroll
            for (int i = 0; i < RB; ++i) {
                const float inv = invs[i];
                unsigned pk = *(const unsigned*)&Sraw[i][t * 2];
                floatx2 pv = { bf2f((unsigned short)(pk & 0xFFFFu)) * inv,
                               bf2f((unsigned short)(pk >> 16)) * inv };
                __builtin_nontemporal_store(
                    pv, (floatx2*)(prow + (size_t)i * SEQ + t * 2));
            }
        }

        // ---- Pass 3: O = (E V) * inv. m-range split across wave halves ----
        const int hm = w >> 2;            // m-half 0/1
        const int c  = (w & 3) * 16;      // output col slice
        floatx4 acco = {0.f, 0.f, 0.f, 0.f};
        const unsigned short* vcol = vbase + (size_t)(c + ln) * SEQ;
        #pragma unroll 2
        for (int mc = 0; mc < 8; ++mc) {
            #pragma unroll
            for (int s = 0; s < 2; ++s) {
                const int kk = hm * 512 + mc * 64 + s * 32 + qd * 8;
                shortx8 af  = *(const shortx8*)&Sraw[ln][kk];     // A[m=ln][k]
                shortx8 bfv = *(const shortx8*)(vcol + kk);       // B[k][n=c+ln]
                acco = __builtin_amdgcn_mfma_f32_16x16x32_bf16(af, bfv, acco,
                                                               0, 0, 0);
            }
        }
        if (hm == 1) {
            #pragma unroll
            for (int r = 0; r < 4; ++r) Opart[qd * 4 + r][c + ln] = acco[r];
        }
        __syncthreads();
        if (hm == 0) {
            #pragma unroll
            for (int r = 0; r < 4; ++r) {
                int row = qd * 4 + r;
                float ov = (acco[r] + Opart[row][c + ln]) * invs[row];
                __builtin_nontemporal_store(
                    ov, out + ((size_t)(b * SEQ + n0 + row)) * CH
                            + h * DH + c + ln);
            }
        }
        // No extra barrier needed: all Sraw/invs/Opart reads of head h
        // complete before the barrier above; next head's writes to each
        // are gated behind its own pass-1/pass-2 barriers.
    }
}

extern "C" void kernel_launch(void* const* d_in, const int* in_sizes, int n_in,
                              void* d_out, int out_size, void* d_ws, size_t ws_size,
                              hipStream_t stream) {
    const float* q    = (const float*)d_in[0];
    const float* k    = (const float*)d_in[1];
    const float* v    = (const float*)d_in[2];
    const void*  mask = d_in[3];
    const float* dis  = (const float*)d_in[4];
    float* out  = (float*)d_out;
    float* pout = out + (size_t)BATCH * SEQ * CH;   // p_attn after out

    // workspace staging: qb | kb | vt, each 2M bf16 (4 MB) => 12 MB total
    unsigned short* qb  = (unsigned short*)d_ws;
    unsigned short* kbw = qb  + (size_t)BATCH * SEQ * CH;
    unsigned short* vtw = kbw + (size_t)BATCH * SEQ * CH;
    (void)ws_size;

    prep<<<2560, 256, 0, stream>>>(q, k, v, qb, kbw, vtw);
    attn_mfma<<<BATCH * (SEQ / RB), NTHR, 0, stream>>>(
        qb, kbw, vtw, mask, dis, out, pout);
}